// Round 10
// baseline (135.467 us; speedup 1.0000x reference)
//
#include <hip/hip_runtime.h>
#include <hip/hip_bf16.h>

#define M 8192
#define N 8192
#define K 512
#define BM 128
#define BN 128
#define BK 32
#define NT 16  // K-steps

typedef __attribute__((ext_vector_type(8))) short bf16x8;
typedef __attribute__((ext_vector_type(4))) float f32x4;
typedef __attribute__((ext_vector_type(4))) unsigned short us4;

// Raw barrier: wait only LDS ops (ds_writes visible), leave VMEM in flight.
#define BARRIER_LGKM()                                 \
  do {                                                 \
    asm volatile("s_waitcnt lgkmcnt(0)" ::: "memory"); \
    __builtin_amdgcn_s_barrier();                      \
    asm volatile("" ::: "memory");                     \
  } while (0)

__device__ inline us4 cvt4(f32x4 v) {
  us4 o;
#pragma unroll
  for (int i = 0; i < 4; ++i) {
    __hip_bfloat16 b = __float2bfloat16(v[i]);
    o[i] = *(unsigned short*)&b;
  }
  return o;
}

// Fully fused: f32 inputs -> (inline bf16 cast + LDS stage) -> MFMA GEMM,
// norms accumulated during staging, epilogue divides by norm product.
// 2048 blocks x 512 thr (8 waves, wave tile 64x32), 2 blocks/CU.
// Staging: reg-staged (global f32 -> cvt -> ds_write), 3-buffer rotation,
// one lgkm-only barrier per K-step; loads for step t+1 issued at step t
// (compiler-managed vmcnt). LDS swizzle: 16B slot s' = s ^ ((row>>1)&3)
// on both ds_write and ds_read -> max 2-way bank aliasing (free).
__global__ __launch_bounds__(512, 4) void fused_kernel(const float* __restrict__ Af,
                                                       const float* __restrict__ Bf,
                                                       float* __restrict__ C) {
  __shared__ __align__(16) unsigned short As[3][BM * BK];  // 3 x 8 KB
  __shared__ __align__(16) unsigned short Bs[3][BN * BK];  // 3 x 8 KB
  __shared__ float w1s[BM], w2s[BN];

  const int tid = threadIdx.x;
  const int wave = tid >> 6;
  const int lane = tid & 63;
  const int wM = wave >> 2;  // 0..1 : 64-row half
  const int wN = wave & 3;   // 0..3 : 32-col quarter
  const int fr = lane & 15;
  const int fq = lane >> 4;

  // Two-level XCD swizzle (r9): xcd owns col-panels [xcd*8, xcd*8+8).
  const int xcd = blockIdx.x & 7;
  const int idx = blockIdx.x >> 3;              // 0..255
  const int bRow = (idx >> 3) * BM;             // 64 row-panels
  const int bCol = (xcd * 8 + (idx & 7)) * BN;  // 64 col-panels

  // Staging mapping: flat4 = tid + 512*i (i=0,1): row = flat4>>3, k4 = tid&7.
  // Per load instr: 8 rows x 128 B contiguous f32 -> fully coalesced.
  const int srow = tid >> 3;  // 0..63 (i=0); +64 for i=1
  const int k4 = tid & 7;

  // LDS byte offset for (row, k4), swizzled at 16B-slot granularity.
  auto offRC = [&](int row) {
    return row * 64 + (((k4 >> 1) ^ ((row >> 1) & 3)) * 16) + (k4 & 1) * 8;
  };
  const int offA0 = offRC(srow), offA1 = offRC(srow + 64);

  f32x4 ra0, ra1, rb0, rb1;
  auto loadR = [&](int t) {
    const float* pa = Af + (size_t)(bRow + srow) * K + t * BK + k4 * 4;
    ra0 = *(const f32x4*)pa;
    ra1 = *(const f32x4*)(pa + (size_t)64 * K);
    const float* pb = Bf + (size_t)(bCol + srow) * K + t * BK + k4 * 4;
    rb0 = *(const f32x4*)pb;
    rb1 = *(const f32x4*)(pb + (size_t)64 * K);
  };

  float ssA0 = 0.f, ssA1 = 0.f, ssB0 = 0.f, ssB1 = 0.f;
  auto stage = [&](int buf) {
    *(us4*)((char*)&As[buf][0] + offA0) = cvt4(ra0);
    *(us4*)((char*)&As[buf][0] + offA1) = cvt4(ra1);
    *(us4*)((char*)&Bs[buf][0] + offA0) = cvt4(rb0);
    *(us4*)((char*)&Bs[buf][0] + offA1) = cvt4(rb1);
    ssA0 += ra0[0]*ra0[0] + ra0[1]*ra0[1] + ra0[2]*ra0[2] + ra0[3]*ra0[3];
    ssA1 += ra1[0]*ra1[0] + ra1[1]*ra1[1] + ra1[2]*ra1[2] + ra1[3]*ra1[3];
    ssB0 += rb0[0]*rb0[0] + rb0[1]*rb0[1] + rb0[2]*rb0[2] + rb0[3]*rb0[3];
    ssB1 += rb1[0]*rb1[0] + rb1[1]*rb1[1] + rb1[2]*rb1[2] + rb1[3]*rb1[3];
  };

  auto ldfrag = [&](const unsigned short* buf, int row) -> bf16x8 {
    return *(const bf16x8*)((const char*)buf + row * 64 +
                            ((fq ^ ((row >> 1) & 3)) * 16));
  };

  f32x4 acc[4][2] = {};

  // Prologue: stage step 0, issue loads for step 1.
  loadR(0);
  stage(0);
  loadR(1);
  BARRIER_LGKM();

#pragma unroll
  for (int t = 0; t < NT; ++t) {
    const int cur = t % 3, nxt = (t + 1) % 3;

    bf16x8 a[4], b[2];
#pragma unroll
    for (int m = 0; m < 4; ++m) a[m] = ldfrag(&As[cur][0], wM * 64 + m * 16 + fr);
#pragma unroll
    for (int n = 0; n < 2; ++n) b[n] = ldfrag(&Bs[cur][0], wN * 32 + n * 16 + fr);

    if (t + 1 < NT) {
      stage(nxt);               // consumes R(t+1); compiler inserts vmcnt wait
      if (t + 2 < NT) loadR(t + 2);
    }

    __builtin_amdgcn_s_setprio(1);
#pragma unroll
    for (int m = 0; m < 4; ++m)
#pragma unroll
      for (int n = 0; n < 2; ++n)
        acc[m][n] = __builtin_amdgcn_mfma_f32_16x16x32_bf16(a[m], b[n], acc[m][n], 0, 0, 0);
    __builtin_amdgcn_s_setprio(0);

    if (t < NT - 1) BARRIER_LGKM();
  }

  // Norms: reduce sum-of-squares across the 8 lanes (k4 groups) per row.
#pragma unroll
  for (int off = 1; off < 8; off <<= 1) {
    ssA0 += __shfl_xor(ssA0, off, 64);
    ssA1 += __shfl_xor(ssA1, off, 64);
    ssB0 += __shfl_xor(ssB0, off, 64);
    ssB1 += __shfl_xor(ssB1, off, 64);
  }
  if (k4 == 0) {
    w1s[srow]      = 1.0f / fmaxf(sqrtf(ssA0), 1e-4f);
    w1s[srow + 64] = 1.0f / fmaxf(sqrtf(ssA1), 1e-4f);
    w2s[srow]      = 1.0f / fmaxf(sqrtf(ssB0), 1e-4f);
    w2s[srow + 64] = 1.0f / fmaxf(sqrtf(ssB1), 1e-4f);
  }
  BARRIER_LGKM();

  // Epilogue. C/D layout: col = lane&15, row = (lane>>4)*4 + reg.
  float i1v[4][4], i2v[2];
#pragma unroll
  for (int m = 0; m < 4; ++m)
#pragma unroll
    for (int r = 0; r < 4; ++r) i1v[m][r] = w1s[wM * 64 + m * 16 + fq * 4 + r];
#pragma unroll
  for (int n = 0; n < 2; ++n) i2v[n] = w2s[wN * 32 + n * 16 + fr];

#pragma unroll
  for (int m = 0; m < 4; ++m) {
    const int row0 = bRow + wM * 64 + m * 16 + fq * 4;
#pragma unroll
    for (int n = 0; n < 2; ++n) {
      const int col = bCol + wN * 32 + n * 16 + fr;
      f32x4 v = acc[m][n];
#pragma unroll
      for (int r = 0; r < 4; ++r)
        C[(size_t)(row0 + r) * N + col] = v[r] * i1v[m][r] * i2v[n];
    }
  }
}

extern "C" void kernel_launch(void* const* d_in, const int* in_sizes, int n_in,
                              void* d_out, int out_size, void* d_ws, size_t ws_size,
                              hipStream_t stream) {
  (void)in_sizes; (void)n_in; (void)out_size; (void)d_ws; (void)ws_size;
  const float* img = (const float*)d_in[0];
  const float* txt = (const float*)d_in[1];
  float* out = (float*)d_out;

  fused_kernel<<<(M / BM) * (N / BN), 512, 0, stream>>>(img, txt, out);
}